// Round 17
// baseline (1005.313 us; speedup 1.0000x reference)
//
#include <hip/hip_runtime.h>
#include <hip/hip_cooperative_groups.h>
#if __has_include(<hip/hip_fp8.h>)
#include <hip/hip_fp8.h>
#endif

namespace cg = cooperative_groups;

// ---------------------------------------------------------------------------
// MHABlock as ONE cooperative kernel (grid 960x256, 4 blocks/CU @ 40KB LDS):
//   P0 cvt (x,W->bf16, scale in Wq/Wk, l_tot zero)   [3800 logical blocks]
//   P1 gemm QKV (bf16, BK=64, global_load_lds)       [480 active]
//   P2 transpose K'/V'->fp8, Q->fp8, vals zero       [1920 logical]
//   P3 split-K(3) fp8 flash attention (R14 struct)   [960 native]
//   P4 deferred normalize + residual + LayerNorm     [1024 logical]
// phases separated by __threadfence() + grid.sync(). Fallback: 5 dispatches.
// ---------------------------------------------------------------------------

typedef __bf16 bf16x8 __attribute__((ext_vector_type(8)));
typedef __bf16 bf16x4 __attribute__((ext_vector_type(4)));
typedef float  f32x4  __attribute__((ext_vector_type(4)));
typedef unsigned short u16x4 __attribute__((ext_vector_type(4)));
typedef unsigned int   u32x4 __attribute__((ext_vector_type(4)));
typedef long           la64  __attribute__((may_alias));
typedef unsigned int   ua32  __attribute__((may_alias));

#define N_TOK   4096
#define D_MODEL 640
#define DK      64
#define HSLAB   (N_TOK * DK)
#define SQS 0.15014030f   // sqrt(log2(e)/64), folded into Wq AND Wk

#if __has_builtin(__builtin_amdgcn_exp2f)
#define EXP2(x) __builtin_amdgcn_exp2f(x)
#else
#define EXP2(x) exp2f(x)
#endif

struct P {
    const float *x, *Wq, *Wk, *Wv, *gamma, *beta; float* out;
    unsigned short *xb, *wqb, *wkb, *wvb, *Qn, *Kn, *Vn;
    unsigned char *Kp8, *Vp8, *Qf8;
    float *vals, *l_tot;
};

__device__ __forceinline__ P mkp(const float* x, const float* Wq, const float* Wk,
                                 const float* Wv, const float* gamma, const float* beta,
                                 float* out, char* ws) {
    P p;
    p.x = x; p.Wq = Wq; p.Wk = Wk; p.Wv = Wv; p.gamma = gamma; p.beta = beta; p.out = out;
    p.xb  = (unsigned short*)(ws);
    p.Qf8 = (unsigned char*)(ws);                 // overlays xb (dead after gemm)
    p.wqb = (unsigned short*)(ws + 5242880);
    p.wkb = (unsigned short*)(ws + 6062080);
    p.wvb = (unsigned short*)(ws + 6881280);
    p.Qn  = (unsigned short*)(ws + 7700480);
    p.Kp8 = (unsigned char*)(ws + 12943360);
    p.Vp8 = (unsigned char*)(ws + 18186240);
    p.Kn  = (unsigned short*)(ws + 23429120);     // aliases vals (exactly)
    p.Vn  = (unsigned short*)(ws + 28672000);
    p.vals  = (float*)(ws + 23429120);
    p.l_tot = (float*)(ws + 33914880);
    return p;
}

__device__ __forceinline__ void stage16(const void* g, void* lds_uniform) {
    __builtin_amdgcn_global_load_lds(
        (const __attribute__((address_space(1))) unsigned int*)g,
        (__attribute__((address_space(3))) unsigned int*)lds_uniform, 16, 0, 0);
}

__device__ __forceinline__ u16x4 cvt4(f32x4 v) {
    return __builtin_bit_cast(u16x4, __builtin_convertvector(v, bf16x4));
}

__device__ __forceinline__ unsigned int pk_fp8(f32x4 v) {
#if __has_builtin(__builtin_amdgcn_cvt_pk_fp8_f32)
    int r = 0;
    r = __builtin_amdgcn_cvt_pk_fp8_f32(v[0], v[1], r, false);
    r = __builtin_amdgcn_cvt_pk_fp8_f32(v[2], v[3], r, true);
    return (unsigned int)r;
#else
    union { unsigned char b[4]; unsigned int u; } x;
    x.b[0] = __hip_fp8_e4m3(v[0]).__x;
    x.b[1] = __hip_fp8_e4m3(v[1]).__x;
    x.b[2] = __hip_fp8_e4m3(v[2]).__x;
    x.b[3] = __hip_fp8_e4m3(v[3]).__x;
    return x.u;
#endif
}

// ------------------------------ P0: cvt ------------------------------------
__device__ __forceinline__ void phase_cvt(const P& p) {
    for (int vb = blockIdx.x; vb < 3800; vb += gridDim.x) {
        int i = vb * 256 + threadIdx.x;
        if (i >= 962560) {
            ((f32x4*)p.l_tot)[i - 962560] = (f32x4){0.f, 0.f, 0.f, 0.f};
            continue;
        }
        const float* s; unsigned short* d; int off; float scl = 1.0f;
        if (i < 655360) { s = p.x; d = p.xb; off = i; }
        else {
            int j = i - 655360;
            int w = j / 102400; off = j - w * 102400;
            s = (w == 0) ? p.Wq : (w == 1) ? p.Wk : p.Wv;
            d = (w == 0) ? p.wqb : (w == 1) ? p.wkb : p.wvb;
            if (w < 2) scl = SQS;
        }
        f32x4 v = ((const f32x4*)s)[off];
        v[0] *= scl; v[1] *= scl; v[2] *= scl; v[3] *= scl;
        ((u16x4*)d)[off] = cvt4(v);
    }
}

// ------------------------------ P1: gemm -----------------------------------
__device__ __forceinline__ void phase_gemm(char* smraw, const P& p, int b) {
    if (b >= 480) return;
    const int g = b & 31;            // m-tile (XCD-pinned)
    const int r = b >> 5;
    const int mode = r / 5;
    const int m0 = g * 128;
    const int n0 = (r % 5) * 128;
    const unsigned short* W = (mode == 0) ? p.wqb : (mode == 1) ? p.wkb : p.wvb;
    unsigned short*       C = (mode == 0) ? p.Qn  : (mode == 1) ? p.Kn  : p.Vn;

    unsigned short* As = (unsigned short*)smraw;          // 16KB
    unsigned short* Bs = (unsigned short*)(smraw + 16384);

    const int tid  = threadIdx.x;
    const int lane = tid & 63;
    const int wave = tid >> 6;
    const int quad = lane >> 4, l16 = lane & 15;
    const int wm = (wave >> 1) * 64, wn = (wave & 1) * 64;
    const int swz = l16 & 7;

    f32x4 acc[4][4] = {};

    int prow[4], pcol[4], lbase[4];
    for (int j = 0; j < 4; j++) {
        int c = j * 256 + tid;
        prow[j] = c >> 3;
        pcol[j] = ((c & 7) ^ (prow[j] & 7)) * 8;
        lbase[j] = (j * 256 + wave * 64) * 8;
    }

    for (int kt = 0; kt < D_MODEL; kt += 64) {
        __syncthreads();
        for (int j = 0; j < 4; j++) {
            stage16(&p.xb[(size_t)(m0 + prow[j]) * D_MODEL + kt + pcol[j]], As + lbase[j]);
            stage16(&W   [(size_t)(n0 + prow[j]) * D_MODEL + kt + pcol[j]], Bs + lbase[j]);
        }
        __syncthreads();

        for (int s = 0; s < 2; s++) {
            bf16x8 af[4], bfr[4];
            for (int mi = 0; mi < 4; mi++) {
                int row = wm + mi * 16 + l16;
                af[mi] = *(const bf16x8*)&As[row * 64 + (((s << 2) + quad) ^ swz) * 8];
            }
            for (int ni = 0; ni < 4; ni++) {
                int row = wn + ni * 16 + l16;
                bfr[ni] = *(const bf16x8*)&Bs[row * 64 + (((s << 2) + quad) ^ swz) * 8];
            }
            for (int mi = 0; mi < 4; mi++)
                for (int ni = 0; ni < 4; ni++)
                    acc[mi][ni] = __builtin_amdgcn_mfma_f32_16x16x32_bf16(af[mi], bfr[ni], acc[mi][ni], 0, 0, 0);
        }
    }

    for (int mi = 0; mi < 4; mi++)
        for (int ni = 0; ni < 4; ni++) {
            u16x4 cv = cvt4(acc[mi][ni]);
            for (int r2 = 0; r2 < 4; r2++) {
                int row = m0 + wm + mi * 16 + quad * 4 + r2;
                int col = n0 + wn + ni * 16 + l16;
                C[(size_t)row * D_MODEL + col] = cv[r2];
            }
        }
}

// ---------------------------- P2: transpose --------------------------------
__device__ __forceinline__ void phase_transpose(char* smraw, const P& p) {
    unsigned short (*T)[66] = (unsigned short(*)[66])smraw;   // 64x66 = 8448B
    const int t = threadIdx.x;

    for (int zb = blockIdx.x; zb < 1920; zb += gridDim.x) {
        const int z  = zb >> 6;      // 0..29
        const int xb = zb & 63;

        if (z >= 20) {   // Q convert + (no T use)
            const size_t base = (size_t)(z - 20) * HSLAB + xb * 4096 + t * 16;
            bf16x8 v0 = *(const bf16x8*)&p.Qn[base];
            bf16x8 v1 = *(const bf16x8*)&p.Qn[base + 8];
            f32x4 a = {(float)v0[0], (float)v0[1], (float)v0[2], (float)v0[3]};
            f32x4 b = {(float)v0[4], (float)v0[5], (float)v0[6], (float)v0[7]};
            f32x4 c = {(float)v1[0], (float)v1[1], (float)v1[2], (float)v1[3]};
            f32x4 d = {(float)v1[4], (float)v1[5], (float)v1[6], (float)v1[7]};
            u32x4 o = {pk_fp8(a), pk_fp8(b), pk_fp8(c), pk_fp8(d)};
            *(u32x4*)&p.Qf8[base] = o;
            continue;
        }

        const unsigned short* src; unsigned char* dst;
        int Cc, r0, c0;
        if (z < 10) { src = p.Kn; dst = p.Kp8; Cc = 4096; r0 = 0; c0 = xb * 64; }
        else        { src = p.Vn; dst = p.Vp8; Cc = 64;   r0 = xb * 64; c0 = 0; }
        const size_t hb = (size_t)(z % 10) * HSLAB;
        const int rr = t >> 3, c8 = (t & 7) * 8;

        for (int hf = 0; hf < 2; hf++) {
            int r = rr + hf * 32;
            bf16x8 v = *(const bf16x8*)&src[hb + (size_t)(r0 + r) * Cc + c0 + c8];
            for (int j = 0; j < 8; j++) T[r][c8 + j] = ((unsigned short*)&v)[j];
        }
        __syncthreads();
        const bf16x8 zz = {};
        for (int hf = 0; hf < 2; hf++) {
            int r = rr + hf * 32;
            *(bf16x8*)&((unsigned short*)src)[hb + (size_t)(r0 + r) * Cc + c0 + c8] = zz;
        }
        for (int hf = 0; hf < 2; hf++) {
            int oc = rr + hf * 32;
            f32x4 lo, hi;
            for (int j = 0; j < 4; j++) {
                lo[j] = __builtin_bit_cast(float, (unsigned int)T[c8 + j][oc] << 16);
                hi[j] = __builtin_bit_cast(float, (unsigned int)T[c8 + 4 + j][oc] << 16);
            }
            uint2 ov; ov.x = pk_fp8(lo); ov.y = pk_fp8(hi);
            size_t dcol = (z < 10) ? ((size_t)(c0 + oc) * 64 + r0 + c8)
                                   : ((size_t)oc * 4096 + r0 + c8);
            *(uint2*)&dst[hb + dcol] = ov;
        }
        __syncthreads();   // protect T before next loop iteration
    }
}

// ------------------------------ P3: attn -----------------------------------
__device__ __forceinline__ void phase_attn(char* smraw, const P& p, int bx, int by) {
    const int h  = bx >> 5;
    const int qt = bx & 31;
    const int ntile = (by == 2) ? 10 : 11;
    const int tile0 = by * 11;
    const int lane = threadIdx.x & 63;
    const int wave = threadIdx.x >> 6;
    const int quad = lane >> 4, l16 = lane & 15;
    const size_t hoff = (size_t)h * HSLAB;

    unsigned char* const Kb0 = (unsigned char*)smraw;       // 8KB ping
    unsigned char* const Kb1 = (unsigned char*)smraw + 8192;
    unsigned char* const Vt  = (unsigned char*)smraw + 16384;
    unsigned char* const Pw  = (unsigned char*)smraw + 24576 + wave * 4096;

    const int qbase = qt * 128 + wave * 32;
    long qd[2][2];
    for (int g = 0; g < 2; g++) {
        const unsigned char* qp = p.Qf8 + hoff + (size_t)(qbase + g * 16 + l16) * 64 + quad * 8;
        qd[g][0] = *(const la64*)(qp);
        qd[g][1] = *(const la64*)(qp + 32);
    }

    f32x4 o[2][4] = {};
    f32x4 ol[2] = {};
    const long ONES8 = 0x3838383838383838L;

    const int cA = wave * 64 + lane, cB = cA + 256;
    const int kKeyA = ((cA >> 5) << 3) + (cA & 7), kCiA = (cA >> 3) & 3;
    const int kKeyB = ((cB >> 5) << 3) + (cB & 7), kCiB = (cB >> 3) & 3;
    const int vDkA  = ((cA >> 6) << 3) + (cA & 7), vCvA = (cA >> 3) & 7;
    const int vDkB  = ((cB >> 6) << 3) + (cB & 7), vCvB = (cB >> 3) & 7;

    const int kfb = (l16 >> 3) * 512 + (quad >> 1) * 128 + (l16 & 7) * 16 + (quad & 1) * 8;
    const int vfb = (l16 >> 3) * 1024 + (quad >> 1) * 128 + (l16 & 7) * 16 + (quad & 1) * 8;

    {
        const int keyb = tile0 << 7;
        stage16(p.Kp8 + hoff + (size_t)(keyb + kKeyA) * 64 + kCiA * 16, Kb0 + wave * 1024);
        stage16(p.Kp8 + hoff + (size_t)(keyb + kKeyB) * 64 + kCiB * 16, Kb0 + 4096 + wave * 1024);
    }

    for (int t = 0; t < ntile; t++) {
        const int keyb = (tile0 + t) << 7;
        unsigned char* const Kcur = (t & 1) ? Kb1 : Kb0;

        __syncthreads();

        if (t + 1 < ntile) {
            const int keyn = (tile0 + t + 1) << 7;
            unsigned char* const Knext = (t & 1) ? Kb0 : Kb1;
            stage16(p.Kp8 + hoff + (size_t)(keyn + kKeyA) * 64 + kCiA * 16, Knext + wave * 1024);
            stage16(p.Kp8 + hoff + (size_t)(keyn + kKeyB) * 64 + kCiB * 16, Knext + 4096 + wave * 1024);
        }
        stage16(p.Vp8 + hoff + (size_t)vDkA * N_TOK + keyb + vCvA * 16, Vt + wave * 1024);
        stage16(p.Vp8 + hoff + (size_t)vDkB * N_TOK + keyb + vCvB * 16, Vt + 4096 + wave * 1024);

        for (int ni = 0; ni < 8; ni++) {
            const unsigned char* kp = Kcur + ni * 1024 + kfb;
            long a0 = *(const la64*)(kp);
            long a1 = *(const la64*)(kp + 256);
            for (int g = 0; g < 2; g++) {
                f32x4 s = {};
                s = __builtin_amdgcn_mfma_f32_16x16x32_fp8_fp8(a0, qd[g][0], s, 0, 0, 0);
                s = __builtin_amdgcn_mfma_f32_16x16x32_fp8_fp8(a1, qd[g][1], s, 0, 0, 0);
                f32x4 pv;
                for (int r = 0; r < 4; r++) pv[r] = EXP2(s[r]);
                *(ua32*)(Pw + (ni * 2 + (quad >> 1)) * 256 +
                         (g * 16 + l16) * 8 + (quad & 1) * 4) = pk_fp8(pv);
            }
        }

        __syncthreads();

        for (int ks = 0; ks < 4; ks++) {
            long vf[4];
            for (int nd = 0; nd < 4; nd++)
                vf[nd] = *(const la64*)(Vt + nd * 2048 + ks * 256 + vfb);
            for (int g = 0; g < 2; g++) {
                long pf = *(const la64*)(Pw + (ks * 4 + quad) * 256 + (g * 16 + l16) * 8);
                ol[g] = __builtin_amdgcn_mfma_f32_16x16x32_fp8_fp8(pf, ONES8, ol[g], 0, 0, 0);
                for (int nd = 0; nd < 4; nd++)
                    o[g][nd] = __builtin_amdgcn_mfma_f32_16x16x32_fp8_fp8(pf, vf[nd], o[g][nd], 0, 0, 0);
            }
        }
    }

    if (l16 == 0)
        for (int g = 0; g < 2; g++)
            for (int r = 0; r < 4; r++)
                atomicAdd(&p.l_tot[(h << 12) + qbase + g * 16 + quad * 4 + r], ol[g][r]);

    for (int g = 0; g < 2; g++)
        for (int nd = 0; nd < 4; nd++)
            for (int r = 0; r < 4; r++) {
                int q = qbase + g * 16 + quad * 4 + r;
                atomicAdd(&p.vals[hoff + (size_t)q * DK + nd * 16 + l16], o[g][nd][r]);
            }
}

// ------------------------------- P4: ln ------------------------------------
__device__ __forceinline__ void phase_ln(const P& p) {
    const int wave = threadIdx.x >> 6, lane = threadIdx.x & 63;
    for (int rb = blockIdx.x; rb < 1024; rb += gridDim.x) {
        const int row = rb * 4 + wave;
        const float* v  = p.vals + (size_t)row * D_MODEL;
        const float* xr = p.x    + (size_t)row * D_MODEL;

        float t[10];
        float s = 0.f;
        for (int i = 0; i < 10; i++) {
            float linv = 1.0f / p.l_tot[row * 10 + i];
            t[i] = v[lane + i * 64] * linv + xr[lane + i * 64];
            s += t[i];
        }
        for (int off = 32; off; off >>= 1) s += __shfl_xor(s, off, 64);
        float mean = s * (1.0f / 640.0f);
        float s2 = 0.f;
        for (int i = 0; i < 10; i++) { float d = t[i] - mean; s2 += d * d; }
        for (int off = 32; off; off >>= 1) s2 += __shfl_xor(s2, off, 64);
        float inv = rsqrtf(s2 * (1.0f / 640.0f) + 1e-5f);

        float* orow = p.out + (size_t)row * D_MODEL;
        for (int i = 0; i < 10; i++) {
            int c = lane + i * 64;
            orow[c] = (t[i] - mean) * inv * p.gamma[c] + p.beta[c];
        }
    }
}

// ------------------------- cooperative mono kernel -------------------------
__global__ void __launch_bounds__(256, 4) mono(
    const float* x, const float* Wq, const float* Wk, const float* Wv,
    const float* gamma, const float* beta, float* out, char* ws) {
    __shared__ __align__(16) char sm[40960];
    P p = mkp(x, Wq, Wk, Wv, gamma, beta, out, ws);
    cg::grid_group grid = cg::this_grid();

    phase_cvt(p);
    __threadfence(); grid.sync();
    phase_gemm(sm, p, blockIdx.x);
    __threadfence(); grid.sync();
    phase_transpose(sm, p);
    __threadfence(); grid.sync();
    phase_attn(sm, p, blockIdx.x % 320, blockIdx.x / 320);
    __threadfence(); grid.sync();
    phase_ln(p);
}

// ------------------------- fallback standalone kernels ---------------------
__global__ void __launch_bounds__(256) k_cvt(const float* x, const float* Wq,
    const float* Wk, const float* Wv, const float* gamma, const float* beta,
    float* out, char* ws) {
    P p = mkp(x, Wq, Wk, Wv, gamma, beta, out, ws);
    phase_cvt(p);
}
__global__ void __launch_bounds__(256, 2) k_gemm(const float* x, const float* Wq,
    const float* Wk, const float* Wv, const float* gamma, const float* beta,
    float* out, char* ws) {
    __shared__ __align__(16) char sm[40960];
    P p = mkp(x, Wq, Wk, Wv, gamma, beta, out, ws);
    phase_gemm(sm, p, blockIdx.x);
}
__global__ void __launch_bounds__(256) k_trans(const float* x, const float* Wq,
    const float* Wk, const float* Wv, const float* gamma, const float* beta,
    float* out, char* ws) {
    __shared__ __align__(16) char sm[40960];
    P p = mkp(x, Wq, Wk, Wv, gamma, beta, out, ws);
    phase_transpose(sm, p);
}
__global__ void __launch_bounds__(256, 4) k_attn(const float* x, const float* Wq,
    const float* Wk, const float* Wv, const float* gamma, const float* beta,
    float* out, char* ws) {
    __shared__ __align__(16) char sm[40960];
    P p = mkp(x, Wq, Wk, Wv, gamma, beta, out, ws);
    phase_attn(sm, p, blockIdx.x, blockIdx.y);
}
__global__ void __launch_bounds__(256) k_ln(const float* x, const float* Wq,
    const float* Wk, const float* Wv, const float* gamma, const float* beta,
    float* out, char* ws) {
    P p = mkp(x, Wq, Wk, Wv, gamma, beta, out, ws);
    phase_ln(p);
}

// ------------------------------- launcher ----------------------------------
extern "C" void kernel_launch(void* const* d_in, const int* in_sizes, int n_in,
                              void* d_out, int out_size, void* d_ws, size_t ws_size,
                              hipStream_t stream) {
    const float* x     = (const float*)d_in[0];
    const float* Wq    = (const float*)d_in[1];
    const float* Wk    = (const float*)d_in[2];
    const float* Wv    = (const float*)d_in[3];
    const float* gamma = (const float*)d_in[4];
    const float* beta  = (const float*)d_in[5];
    float* out = (float*)d_out;
    char* ws = (char*)d_ws;

    void* kargs[] = {(void*)&x, (void*)&Wq, (void*)&Wk, (void*)&Wv,
                     (void*)&gamma, (void*)&beta, (void*)&out, (void*)&ws};

    hipError_t e = hipLaunchCooperativeKernel((const void*)mono, dim3(960),
                                              dim3(256), kargs, 0, stream);
    if (e != hipSuccess) {
        // fallback: identical math, 5 dispatches
        k_cvt  <<<3800,        256, 0, stream>>>(x, Wq, Wk, Wv, gamma, beta, out, ws);
        k_gemm <<<480,         256, 0, stream>>>(x, Wq, Wk, Wv, gamma, beta, out, ws);
        k_trans<<<1920,        256, 0, stream>>>(x, Wq, Wk, Wv, gamma, beta, out, ws);
        k_attn <<<dim3(320,3), 256, 0, stream>>>(x, Wq, Wk, Wv, gamma, beta, out, ws);
        k_ln   <<<1024,        256, 0, stream>>>(x, Wq, Wk, Wv, gamma, beta, out, ws);
    }
}

// Round 18
// 151.590 us; speedup vs baseline: 6.6318x; 6.6318x over previous
//
#include <hip/hip_runtime.h>
#if __has_include(<hip/hip_fp8.h>)
#include <hip/hip_fp8.h>
#endif

// ---------------------------------------------------------------------------
// MHABlock: cvt (+l_tot zero, sqrt-softmax-scale folded into Wq AND Wk) ->
// QKV GEMM (bf16, BK=64, global_load_lds, XCD-pinned m-tiles) ->
// fused K/V transpose + fp8 convert (+Q->fp8, +vals zero) -> split-K(3) fp8
// flash attention (R14 2-barrier ping-pong; P layout rotated by (pu&3)*8 to
// break the 4-way P-read bank conflict) -> deferred normalize + LN.
// ---------------------------------------------------------------------------

typedef __bf16 bf16x8 __attribute__((ext_vector_type(8)));
typedef __bf16 bf16x4 __attribute__((ext_vector_type(4)));
typedef float  f32x4  __attribute__((ext_vector_type(4)));
typedef unsigned short u16x4 __attribute__((ext_vector_type(4)));
typedef unsigned int   u32x4 __attribute__((ext_vector_type(4)));
typedef long           la64  __attribute__((may_alias));
typedef unsigned int   ua32  __attribute__((may_alias));

#define N_TOK   4096
#define D_MODEL 640
#define DK      64
#define HSLAB   (N_TOK * DK)
// sqrt(log2(e)/64): folded into BOTH Wq and Wk -> logits arrive base-2 scaled
#define SQS 0.15014030f

#if __has_builtin(__builtin_amdgcn_exp2f)
#define EXP2(x) __builtin_amdgcn_exp2f(x)
#else
#define EXP2(x) exp2f(x)
#endif

__device__ __forceinline__ void stage16(const void* g, void* lds_uniform) {
    __builtin_amdgcn_global_load_lds(
        (const __attribute__((address_space(1))) unsigned int*)g,
        (__attribute__((address_space(3))) unsigned int*)lds_uniform, 16, 0, 0);
}

__device__ __forceinline__ u16x4 cvt4(f32x4 v) {
    return __builtin_bit_cast(u16x4, __builtin_convertvector(v, bf16x4));
}

__device__ __forceinline__ unsigned int pk_fp8(f32x4 v) {
#if __has_builtin(__builtin_amdgcn_cvt_pk_fp8_f32)
    int r = 0;
    r = __builtin_amdgcn_cvt_pk_fp8_f32(v[0], v[1], r, false);
    r = __builtin_amdgcn_cvt_pk_fp8_f32(v[2], v[3], r, true);
    return (unsigned int)r;
#else
    union { unsigned char b[4]; unsigned int u; } x;
    x.b[0] = __hip_fp8_e4m3(v[0]).__x;
    x.b[1] = __hip_fp8_e4m3(v[1]).__x;
    x.b[2] = __hip_fp8_e4m3(v[2]).__x;
    x.b[3] = __hip_fp8_e4m3(v[3]).__x;
    return x.u;
#endif
}

// ---------- fused fp32 -> bf16 (x, Wq*s, Wk*s, Wv) + l_tot zeroing ---------
__global__ __launch_bounds__(256) void cvt_all(const float* __restrict__ x,
                                               const float* __restrict__ w0,
                                               const float* __restrict__ w1,
                                               const float* __restrict__ w2,
                                               unsigned short* __restrict__ xb,
                                               unsigned short* __restrict__ d0,
                                               unsigned short* __restrict__ d1,
                                               unsigned short* __restrict__ d2,
                                               f32x4* __restrict__ ltot4) {
    int i = blockIdx.x * 256 + threadIdx.x;
    if (i >= 962560) { ltot4[i - 962560] = (f32x4){0.f, 0.f, 0.f, 0.f}; return; }
    const float* s; unsigned short* d; int off; float scl = 1.0f;
    if (i < 655360) { s = x; d = xb; off = i; }
    else {
        int j = i - 655360;
        int w = j / 102400; off = j - w * 102400;
        s = (w == 0) ? w0 : (w == 1) ? w1 : w2;
        d = (w == 0) ? d0 : (w == 1) ? d1 : d2;
        if (w < 2) scl = SQS;   // Wq, Wk carry sqrt of softmax scale
    }
    f32x4 v = ((const f32x4*)s)[off];
    v[0] *= scl; v[1] *= scl; v[2] *= scl; v[3] *= scl;
    ((u16x4*)d)[off] = cvt4(v);
}

// ------------------------ QKV NT-GEMM: C = x @ W^T -------------------------
// M=4096, N=640, K=640. 128x128 tile, BK=64, 4 waves each 64x64.
// Grid 480 linear, XCD-pinned m-tiles (g = b&31 -> g%8 == XCD id).
__global__ __launch_bounds__(256, 2) void gemm_qkv(
    const unsigned short* __restrict__ xb,
    const unsigned short* __restrict__ wq,
    const unsigned short* __restrict__ wk,
    const unsigned short* __restrict__ wv,
    unsigned short* __restrict__ Qo,
    unsigned short* __restrict__ Ko,
    unsigned short* __restrict__ Vo) {
    const int b = blockIdx.x;
    const int g = b & 31;            // m-tile (XCD-pinned)
    const int r = b >> 5;            // 0..14 = (mode, n-tile)
    const int mode = r / 5;
    const int m0 = g * 128;
    const int n0 = (r % 5) * 128;
    const unsigned short* W = (mode == 0) ? wq : (mode == 1) ? wk : wv;
    unsigned short*       C = (mode == 0) ? Qo : (mode == 1) ? Ko : Vo;

    __shared__ unsigned short As[8192];   // 128 rows x 64
    __shared__ unsigned short Bs[8192];

    const int tid  = threadIdx.x;
    const int lane = tid & 63;
    const int wave = tid >> 6;
    const int quad = lane >> 4, l16 = lane & 15;
    const int wm = (wave >> 1) * 64, wn = (wave & 1) * 64;
    const int swz = l16 & 7;

    f32x4 acc[4][4] = {};

    int prow[4], pcol[4], lbase[4];
    for (int j = 0; j < 4; j++) {
        int p = j * 256 + tid;
        prow[j] = p >> 3;
        pcol[j] = ((p & 7) ^ (prow[j] & 7)) * 8;
        lbase[j] = (j * 256 + wave * 64) * 8;
    }

    for (int kt = 0; kt < D_MODEL; kt += 64) {
        __syncthreads();
        for (int j = 0; j < 4; j++) {
            stage16(&xb[(size_t)(m0 + prow[j]) * D_MODEL + kt + pcol[j]], As + lbase[j]);
            stage16(&W [(size_t)(n0 + prow[j]) * D_MODEL + kt + pcol[j]], Bs + lbase[j]);
        }
        __syncthreads();

        for (int s = 0; s < 2; s++) {
            bf16x8 af[4], bfr[4];
            for (int mi = 0; mi < 4; mi++) {
                int row = wm + mi * 16 + l16;
                af[mi] = *(const bf16x8*)&As[row * 64 + (((s << 2) + quad) ^ swz) * 8];
            }
            for (int ni = 0; ni < 4; ni++) {
                int row = wn + ni * 16 + l16;
                bfr[ni] = *(const bf16x8*)&Bs[row * 64 + (((s << 2) + quad) ^ swz) * 8];
            }
            for (int mi = 0; mi < 4; mi++)
                for (int ni = 0; ni < 4; ni++)
                    acc[mi][ni] = __builtin_amdgcn_mfma_f32_16x16x32_bf16(af[mi], bfr[ni], acc[mi][ni], 0, 0, 0);
        }
    }

    for (int mi = 0; mi < 4; mi++)
        for (int ni = 0; ni < 4; ni++) {
            u16x4 cv = cvt4(acc[mi][ni]);
            for (int r2 = 0; r2 < 4; r2++) {
                int row = m0 + wm + mi * 16 + quad * 4 + r2;
                int col = n0 + wn + ni * 16 + l16;
                C[(size_t)row * D_MODEL + col] = cv[r2];
            }
        }
}

// ------ fused per-head transpose -> fp8 (K',V') + Q->fp8 + vals zero -------
__global__ __launch_bounds__(256) void transpose_kv(
    const unsigned short* __restrict__ Kn, unsigned char* __restrict__ Kp8,
    const unsigned short* __restrict__ Vn, unsigned char* __restrict__ Vp8,
    const unsigned short* __restrict__ Qn, unsigned char* __restrict__ Qf8) {
    const int z = blockIdx.z;
    const int t = threadIdx.x;

    if (z >= 20) {   // Q convert: head slab, flat
        const size_t base = (size_t)(z - 20) * HSLAB + blockIdx.x * 4096 + t * 16;
        bf16x8 v0 = *(const bf16x8*)&Qn[base];
        bf16x8 v1 = *(const bf16x8*)&Qn[base + 8];
        f32x4 a = {(float)v0[0], (float)v0[1], (float)v0[2], (float)v0[3]};
        f32x4 b = {(float)v0[4], (float)v0[5], (float)v0[6], (float)v0[7]};
        f32x4 c = {(float)v1[0], (float)v1[1], (float)v1[2], (float)v1[3]};
        f32x4 d = {(float)v1[4], (float)v1[5], (float)v1[6], (float)v1[7]};
        u32x4 o = {pk_fp8(a), pk_fp8(b), pk_fp8(c), pk_fp8(d)};
        *(u32x4*)&Qf8[base] = o;
        return;
    }

    __shared__ unsigned short T[64][66];
    const unsigned short* src; unsigned char* dst;
    int R, Cc, r0, c0;
    if (z < 10) { src = Kn; dst = Kp8; R = 64;   Cc = 4096; r0 = 0; c0 = blockIdx.x * 64; }
    else        { src = Vn; dst = Vp8; R = 4096; Cc = 64;   r0 = blockIdx.x * 64; c0 = 0; }
    const size_t hb = (size_t)(z % 10) * HSLAB;
    const int rr = t >> 3, c8 = (t & 7) * 8;

    for (int hf = 0; hf < 2; hf++) {
        int r = rr + hf * 32;
        bf16x8 v = *(const bf16x8*)&src[hb + (size_t)(r0 + r) * Cc + c0 + c8];
        for (int j = 0; j < 8; j++) T[r][c8 + j] = ((unsigned short*)&v)[j];
    }
    __syncthreads();
    // zero the consumed source tile (Kn+Vn exactly cover the fp32 vals buf)
    const bf16x8 zz = {};
    for (int hf = 0; hf < 2; hf++) {
        int r = rr + hf * 32;
        *(bf16x8*)&((unsigned short*)src)[hb + (size_t)(r0 + r) * Cc + c0 + c8] = zz;
    }
    for (int hf = 0; hf < 2; hf++) {
        int oc = rr + hf * 32;
        f32x4 lo, hi;
        for (int j = 0; j < 4; j++) {
            lo[j] = __builtin_bit_cast(float, (unsigned int)T[c8 + j][oc] << 16);
            hi[j] = __builtin_bit_cast(float, (unsigned int)T[c8 + 4 + j][oc] << 16);
        }
        uint2 ov; ov.x = pk_fp8(lo); ov.y = pk_fp8(hi);
        size_t dcol = (z < 10) ? ((size_t)(c0 + oc) * 64 + r0 + c8)
                               : ((size_t)oc * 4096 + r0 + c8);
        *(uint2*)&dst[hb + dcol] = ov;
    }
}

// ------------------------------- attention (fp8) ---------------------------
// grid (320, 3): x = head*32 + qtile(128 rows), y = kpart (11/11/10 tiles of
// 128 keys). 4 waves x 32 q. 2 barriers/tile, ping-pong K, V under S.
// P layout: addr(pu, qq) = pu*256 + ((qq + (pu&3)*8) & 31)*8  [+4 for hi u32]
//   -> write <=2-way, read exactly 2-way (was 4-way).
__global__ __launch_bounds__(256, 4) void attn(
    const unsigned char* __restrict__ Qf8,   // [h][q][dk] fp8
    const unsigned char* __restrict__ Kp8,   // [h][key][dk] fp8
    const unsigned char* __restrict__ Vp8,   // [h][dk][key] fp8
    float* __restrict__ vals,                // pre-zeroed (transpose_kv)
    float* __restrict__ l_tot) {             // pre-zeroed (cvt_all)
    const int h  = blockIdx.x >> 5;
    const int qt = blockIdx.x & 31;
    const int ntile = (blockIdx.y == 2) ? 10 : 11;
    const int tile0 = blockIdx.y * 11;
    const int lane = threadIdx.x & 63;
    const int wave = threadIdx.x >> 6;
    const int quad = lane >> 4, l16 = lane & 15;
    const size_t hoff = (size_t)h * HSLAB;

    __shared__ unsigned char sm[40960];
    unsigned char* const Kb0 = sm;                      // 8KB, ping
    unsigned char* const Kb1 = sm + 8192;               // 8KB, pong
    unsigned char* const Vt  = sm + 16384;              // 8KB
    unsigned char* const Pw  = sm + 24576 + wave * 4096;// 4KB/wave

    const int qbase = qt * 128 + wave * 32;
    long qd[2][2];
    for (int g = 0; g < 2; g++) {
        const unsigned char* qp = Qf8 + hoff + (size_t)(qbase + g * 16 + l16) * 64 + quad * 8;
        qd[g][0] = *(const la64*)(qp);
        qd[g][1] = *(const la64*)(qp + 32);
    }

    f32x4 o[2][4] = {};
    f32x4 ol[2] = {};
    const long ONES8 = 0x3838383838383838L;   // e4m3 1.0 x8

    // staging: LDS chunk c holds: K (key=(c>>5)*8+(c&7), ci=(c>>3)&3)
    //                             V (dk =(c>>6)*8+(c&7), cv=(c>>3)&7)
    const int cA = wave * 64 + lane, cB = cA + 256;
    const int kKeyA = ((cA >> 5) << 3) + (cA & 7), kCiA = (cA >> 3) & 3;
    const int kKeyB = ((cB >> 5) << 3) + (cB & 7), kCiB = (cB >> 3) & 3;
    const int vDkA  = ((cA >> 6) << 3) + (cA & 7), vCvA = (cA >> 3) & 7;
    const int vDkB  = ((cB >> 6) << 3) + (cB & 7), vCvB = (cB >> 3) & 7;

    // fragment-read bases (R10-proven)
    const int kfb = (l16 >> 3) * 512 + (quad >> 1) * 128 + (l16 & 7) * 16 + (quad & 1) * 8;
    const int vfb = (l16 >> 3) * 1024 + (quad >> 1) * 128 + (l16 & 7) * 16 + (quad & 1) * 8;

    // prologue: stage K tile 0 into Kb0
    {
        const int keyb = tile0 << 7;
        stage16(Kp8 + hoff + (size_t)(keyb + kKeyA) * 64 + kCiA * 16, Kb0 + wave * 1024);
        stage16(Kp8 + hoff + (size_t)(keyb + kKeyB) * 64 + kCiB * 16, Kb0 + 4096 + wave * 1024);
    }

    for (int t = 0; t < ntile; t++) {
        const int keyb = (tile0 + t) << 7;
        unsigned char* const Kcur = (t & 1) ? Kb1 : Kb0;

        // K[t] drained by previous mid barrier (or here for t=0); Vt/Pw reads
        // of t-1 complete; K[t+1] buffer free.
        __syncthreads();

        if (t + 1 < ntile) {
            const int keyn = (tile0 + t + 1) << 7;
            unsigned char* const Knext = (t & 1) ? Kb0 : Kb1;
            stage16(Kp8 + hoff + (size_t)(keyn + kKeyA) * 64 + kCiA * 16, Knext + wave * 1024);
            stage16(Kp8 + hoff + (size_t)(keyn + kKeyB) * 64 + kCiB * 16, Knext + 4096 + wave * 1024);
        }
        stage16(Vp8 + hoff + (size_t)vDkA * N_TOK + keyb + vCvA * 16, Vt + wave * 1024);
        stage16(Vp8 + hoff + (size_t)vDkB * N_TOK + keyb + vCvB * 16, Vt + 4096 + wave * 1024);

        // ---- S^T: A = K rows (key), B = Q (pre-scaled); exp2 -> P fp8 ----
        for (int ni = 0; ni < 8; ni++) {
            const unsigned char* kp = Kcur + ni * 1024 + kfb;
            long a0 = *(const la64*)(kp);
            long a1 = *(const la64*)(kp + 256);
            for (int g = 0; g < 2; g++) {
                f32x4 s = {};
                s = __builtin_amdgcn_mfma_f32_16x16x32_fp8_fp8(a0, qd[g][0], s, 0, 0, 0);
                s = __builtin_amdgcn_mfma_f32_16x16x32_fp8_fp8(a1, qd[g][1], s, 0, 0, 0);
                f32x4 pv;
                for (int r = 0; r < 4; r++) pv[r] = EXP2(s[r]);
                const int pu = ni * 2 + (quad >> 1);
                *(ua32*)(Pw + pu * 256 +
                         (((g * 16 + l16) + ((pu & 3) << 3)) & 31) * 8 +
                         (quad & 1) * 4) = pk_fp8(pv);
            }
        }

        // Drains vmcnt (V[t] + K[t+1] staged) and lgkmcnt (P visible).
        __syncthreads();

        // ---- O += P * V, l += P * 1 ----
        for (int ks = 0; ks < 4; ks++) {
            long vf[4];
            for (int nd = 0; nd < 4; nd++)
                vf[nd] = *(const la64*)(Vt + nd * 2048 + ks * 256 + vfb);
            for (int g = 0; g < 2; g++) {
                // reader pu = ks*4+quad -> pu&3 == quad
                long pf = *(const la64*)(Pw + (ks * 4 + quad) * 256 +
                                         (((g * 16 + l16) + (quad << 3)) & 31) * 8);
                ol[g] = __builtin_amdgcn_mfma_f32_16x16x32_fp8_fp8(pf, ONES8, ol[g], 0, 0, 0);
                for (int nd = 0; nd < 4; nd++)
                    o[g][nd] = __builtin_amdgcn_mfma_f32_16x16x32_fp8_fp8(pf, vf[nd], o[g][nd], 0, 0, 0);
            }
        }
    }

    // l: C rows = q offset quad*4+r, cols identical -> write from l16==0
    if (l16 == 0)
        for (int g = 0; g < 2; g++)
            for (int r = 0; r < 4; r++)
                atomicAdd(&l_tot[(h << 12) + qbase + g * 16 + quad * 4 + r], ol[g][r]);

    for (int g = 0; g < 2; g++)
        for (int nd = 0; nd < 4; nd++)
            for (int r = 0; r < 4; r++) {
                int q = qbase + g * 16 + quad * 4 + r;
                atomicAdd(&vals[hoff + (size_t)q * DK + nd * 16 + l16], o[g][nd][r]);
            }
}

// ----------------- deferred normalize + residual + LayerNorm ---------------
__global__ __launch_bounds__(256) void ln_kernel(
    const float* __restrict__ vals, const float* __restrict__ l_tot,
    const float* __restrict__ x,
    const float* __restrict__ gamma, const float* __restrict__ beta,
    float* __restrict__ out) {
    const int wave = threadIdx.x >> 6, lane = threadIdx.x & 63;
    const int row  = blockIdx.x * 4 + wave;
    const float* v  = vals + (size_t)row * D_MODEL;
    const float* xr = x    + (size_t)row * D_MODEL;

    float t[10];
    float s = 0.f;
    for (int i = 0; i < 10; i++) {
        float linv = 1.0f / l_tot[row * 10 + i];
        t[i] = v[lane + i * 64] * linv + xr[lane + i * 64];
        s += t[i];
    }
    for (int off = 32; off; off >>= 1) s += __shfl_xor(s, off, 64);
    float mean = s * (1.0f / 640.0f);
    float s2 = 0.f;
    for (int i = 0; i < 10; i++) { float d = t[i] - mean; s2 += d * d; }
    for (int off = 32; off; off >>= 1) s2 += __shfl_xor(s2, off, 64);
    float inv = rsqrtf(s2 * (1.0f / 640.0f) + 1e-5f);

    float* orow = out + (size_t)row * D_MODEL;
    for (int i = 0; i < 10; i++) {
        int c = lane + i * 64;
        orow[c] = (t[i] - mean) * inv * gamma[c] + beta[c];
    }
}

// ------------------------------- launcher ----------------------------------
extern "C" void kernel_launch(void* const* d_in, const int* in_sizes, int n_in,
                              void* d_out, int out_size, void* d_ws, size_t ws_size,
                              hipStream_t stream) {
    const float* x     = (const float*)d_in[0];
    const float* Wq    = (const float*)d_in[1];
    const float* Wk    = (const float*)d_in[2];
    const float* Wv    = (const float*)d_in[3];
    const float* gamma = (const float*)d_in[4];
    const float* beta  = (const float*)d_in[5];
    float* out = (float*)d_out;

    char* ws = (char*)d_ws;
    unsigned short* xb  = (unsigned short*)(ws);               // 5,242,880 B
    unsigned char*  Qf8 = (unsigned char*)(ws);                // overlays xb (dead after gemm)
    unsigned short* wqb = (unsigned short*)(ws + 5242880);
    unsigned short* wkb = (unsigned short*)(ws + 6062080);
    unsigned short* wvb = (unsigned short*)(ws + 6881280);
    unsigned short* Qn  = (unsigned short*)(ws + 7700480);     // bf16 Q natural
    unsigned char*  Kp8 = (unsigned char*)(ws + 12943360);     // fp8 K' [h][key][dk]
    unsigned char*  Vp8 = (unsigned char*)(ws + 18186240);     // fp8 V' [h][dk][key]
    unsigned short* Kn  = (unsigned short*)(ws + 23429120);    // aliases vals
    unsigned short* Vn  = (unsigned short*)(ws + 28672000);    //  (exactly)
    float*          vals  = (float*)(ws + 23429120);           // 10,485,760 B
    float*          l_tot = (float*)(ws + 33914880);           //   163,840 B

    cvt_all<<<3800, 256, 0, stream>>>(x, Wq, Wk, Wv, xb, wqb, wkb, wvb,
                                      (f32x4*)l_tot);

    gemm_qkv<<<480, 256, 0, stream>>>(xb, wqb, wkb, wvb, Qn, Kn, Vn);

    transpose_kv<<<dim3(64, 1, 30), 256, 0, stream>>>(Kn, Kp8, Vn, Vp8, Qn, Qf8);

    attn<<<dim3(320, 3), 256, 0, stream>>>(Qf8, Kp8, Vp8, vals, l_tot);
    ln_kernel<<<1024, 256, 0, stream>>>(vals, l_tot, x, gamma, beta, out);
}